// Round 8
// baseline (1248.891 us; speedup 1.0000x reference)
//
#include <hip/hip_runtime.h>
#include <hip/hip_bf16.h>
#include <stdint.h>

// SNN forward (snntorch Leaky, subtract reset), T=1024 B=128 NIN=256 HID=1024.
// d_out: out_spikes [T,B,2] | hidden_spikes [T,B,HID] | mem2_f [B,2]
//
// Round-8: hybrid weight fetch. Round-7 was stuck overlapping two 2/3-busy
// pipes (DS 1392cy/t/CU, VALU 1505). Split the gather by k-position:
//   k < 40  -> ds_read_b128 from the 64KB LDS tile (as round-7)
//   k >= 40 -> global_load_dwordx4 of the same W1T row (L2-resident, VMEM pipe)
// Same values, same ascending-k order -> bit-exact. Plus: main/tail
// predication split (only k>=kmin pays cmp+cndmask), strength-reduced
// pointers, global zero-row (W1T row 256 = zeros) for tail predication.
// k_pack/k_h2/k_scan unchanged (L2 reduction tree untouched since round 1).

#define TT  1024
#define BB  128
#define NIN 256
#define HID 1024

#define OFF_HID  262144ULL
#define OFF_MEM2 134479872ULL

// W1T gets 257 rows: rows 0..255 = transpose, row 256 = zeros (predication pad)
__global__ __launch_bounds__(256) void k_transpose(const float* __restrict__ W1,
                                                   float* __restrict__ W1T) {
    int idx = blockIdx.x * 256 + threadIdx.x;     // 263168 = 257*1024 elements
    if (idx >= 257 * 1024) return;
    int j = idx & (HID - 1);
    int i = idx >> 10;
    W1T[(size_t)i * HID + j] = (i < NIN) ? W1[(size_t)j * NIN + i] : 0.0f;
}

__global__ __launch_bounds__(256) void k_pack(const float* __restrict__ x,
                                              unsigned int* __restrict__ cntArr,
                                              unsigned char* __restrict__ idxArr,
                                              int slots) {
    size_t tb = blockIdx.x;                       // T*B blocks, 256 threads = i
    int tid = threadIdx.x;
    int lane = tid & 63, w = tid >> 6;
    float v = x[tb * NIN + tid];
    bool act = v > 0.5f;
    unsigned long long m = __ballot(act);
    __shared__ unsigned int wc[4];
    __shared__ unsigned char sIdx[96];
    if (lane == 0) wc[w] = (unsigned int)__popcll(m);
    __syncthreads();
    unsigned int off = 0;
#pragma unroll
    for (int k = 0; k < 4; ++k) if (k < w) off += wc[k];
    unsigned int cnt = wc[0] + wc[1] + wc[2] + wc[3];
    unsigned int rank = off + (unsigned int)__popcll(m & ((1ull << lane) - 1));
    if (act && rank < (unsigned int)slots) sIdx[rank] = (unsigned char)tid;
    __syncthreads();
    if (tid * 4 < slots)
        ((unsigned int*)(idxArr + tb * (size_t)slots))[tid] = ((const unsigned int*)sIdx)[tid];
    if (tid == 0) cntArr[tb] = cnt;
}

// Workgroup = 4 waves = 4 b's sharing a 64-j chunk of W1T as [257 i][16 quads]
// float4 (64.3 KB LDS). lane = (s=lane>>4 t-subgroup, q=lane&15 quad).
// Grid = 32 bg x 16 jc = 512 wgs -> 2 wg/CU, 2 waves/SIMD.
__global__ __launch_bounds__(256, 2) void k_snn(const float* __restrict__ W1T,
                                                const unsigned int* __restrict__ cntArr,
                                                const unsigned char* __restrict__ idxArr,
                                                const float* __restrict__ x,
                                                const float* __restrict__ b1,
                                                float* __restrict__ outHid,
                                                int slots) {
#pragma clang fp contract(off)
    const int jc   = blockIdx.x & 15;
    const int bg   = blockIdx.x >> 4;
    const int tid  = threadIdx.x;
    const int lane = tid & 63;
    const int wave = tid >> 6;
    const int b    = (bg << 2) + wave;
    const int q    = lane & 15;                   // quad (4 j) within 64-j chunk
    const int s    = lane >> 4;                   // t-subgroup 0..3
    const int jq   = (jc << 6) + (q << 2);

    __shared__ float4 sW4[257 * 16];              // 64.3 KB; row 256 = zeros
    __shared__ float4 sEx[4][64];                 // per-wave exchange scratch

    for (int p = tid; p < NIN * 16; p += 256) {
        int i = p >> 4, qq = p & 15;
        sW4[p] = *reinterpret_cast<const float4*>(W1T + (size_t)i * HID + (jc << 6) + (qq << 2));
    }
    if (tid < 16) sW4[256 * 16 + tid] = make_float4(0.f, 0.f, 0.f, 0.f);
    __syncthreads();

    float mem0 = 0.f, mem1 = 0.f, mem2 = 0.f, mem3 = 0.f;
    const float4 bs = *reinterpret_cast<const float4*>(b1 + jq);
    const int ub = __builtin_amdgcn_readfirstlane(b);
    const int sl = slots;
    const int dwTot = sl >> 2;
    int dwA = q;            if (dwA >= dwTot) dwA = dwTot - 1;
    int dwB = 16 + (q & 7); if (dwB >= dwTot) dwB = dwTot - 1;

    const bool sLo   = (s < 2);
    const bool sEven = ((s & 1) == 0);
    const float* wrow = W1T + jq;                 // per-lane global row base

    // strength-reduced prefetch offsets (bytes), pointing at t = 0..3
    unsigned offCnt = (unsigned)((s * BB + ub) * 4);
    unsigned offA   = (unsigned)((s * BB + ub) * sl + dwA * 4);
    unsigned offB   = (unsigned)((s * BB + ub) * sl + dwB * 4);
    const unsigned stC = (unsigned)(4 * BB * 4);
    const unsigned stL = (unsigned)(4 * BB * sl);

    unsigned cnt_v = *(const unsigned*)((const char*)cntArr + offCnt);
    unsigned vA_v  = *(const unsigned*)(idxArr + offA);
    unsigned vB_v  = *(const unsigned*)(idxArr + offB);

    float* outP = outHid + ((size_t)s * BB + b) * HID + jq;
    const size_t outStep = (size_t)4 * BB * HID;

#define RL(v, l) ((unsigned)__builtin_amdgcn_readlane((int)(v), (l)))
#define FETCH_D(kd, dOut) do {                                                  \
        unsigned _d0, _d1, _d2, _d3;                                            \
        if ((kd) < 16) {                                                        \
            _d0 = RL(vA, (kd));      _d1 = RL(vA, 16 + (kd));                   \
            _d2 = RL(vA, 32 + (kd)); _d3 = RL(vA, 48 + (kd));                   \
        } else { int _m = (kd) - 16;                                            \
            _d0 = RL(vB, _m);        _d1 = RL(vB, 16 + _m);                     \
            _d2 = RL(vB, 32 + _m);   _d3 = RL(vB, 48 + _m); }                   \
        unsigned _dl = sEven ? _d0 : _d1;                                       \
        unsigned _dh = sEven ? _d2 : _d3;                                       \
        dOut = sLo ? _dl : _dh;                                                 \
    } while (0)

#define B_LDS(kd, PRED) do {                                                    \
        unsigned d_; FETCH_D(kd, d_);                                           \
        int kb_ = (kd) << 2;                                                    \
        _Pragma("unroll")                                                       \
        for (int i2 = 0; i2 < 4; ++i2) {                                        \
            unsigned row_ = (d_ >> (8 * i2)) & 255u;                            \
            if (PRED) row_ = ((unsigned)(kb_ + i2) < mylim) ? row_ : 256u;      \
            float4 v_ = sW4[row_ * 16 + q];                                     \
            h0 += v_.x; h1 += v_.y; h2 += v_.z; h3 += v_.w;                     \
        }                                                                       \
    } while (0)

#define B_GLB(kd, PRED) do {                                                    \
        unsigned d_; FETCH_D(kd, d_);                                           \
        int kb_ = (kd) << 2;                                                    \
        float4 va_, vb_, vc_, vd_;                                              \
        unsigned r0_ = d_ & 255u, r1_ = (d_ >> 8) & 255u;                       \
        unsigned r2_ = (d_ >> 16) & 255u, r3_ = d_ >> 24;                       \
        if (PRED) {                                                             \
            r0_ = ((unsigned)(kb_    ) < mylim) ? r0_ : 256u;                   \
            r1_ = ((unsigned)(kb_ + 1) < mylim) ? r1_ : 256u;                   \
            r2_ = ((unsigned)(kb_ + 2) < mylim) ? r2_ : 256u;                   \
            r3_ = ((unsigned)(kb_ + 3) < mylim) ? r3_ : 256u;                   \
        }                                                                       \
        va_ = *reinterpret_cast<const float4*>(wrow + (size_t)r0_ * HID);       \
        vb_ = *reinterpret_cast<const float4*>(wrow + (size_t)r1_ * HID);       \
        vc_ = *reinterpret_cast<const float4*>(wrow + (size_t)r2_ * HID);       \
        vd_ = *reinterpret_cast<const float4*>(wrow + (size_t)r3_ * HID);       \
        h0 += va_.x; h1 += va_.y; h2 += va_.z; h3 += va_.w;                     \
        h0 += vb_.x; h1 += vb_.y; h2 += vb_.z; h3 += vb_.w;                     \
        h0 += vc_.x; h1 += vc_.y; h2 += vc_.z; h3 += vc_.w;                     \
        h0 += vd_.x; h1 += vd_.y; h2 += vd_.z; h3 += vd_.w;                     \
    } while (0)

    const int SPLIT = 10;                         // dwords via LDS (k < 40)

    for (int t = 0; t < TT; t += 4) {
        unsigned cnt = cnt_v, vA = vA_v, vB = vB_v;

        // prefetch t+4 (clamped via zero stride on last iter)
        unsigned st = (t + 4 < TT) ? 1u : 0u;
        offCnt += st * stC; offA += st * stL; offB += st * stL;
        cnt_v = *(const unsigned*)((const char*)cntArr + offCnt);
        vA_v  = *(const unsigned*)(idxArr + offA);
        vB_v  = *(const unsigned*)(idxArr + offB);

        unsigned mylim = cnt < (unsigned)sl ? cnt : (unsigned)sl;
        int l0 = __builtin_amdgcn_readlane((int)mylim, 0);
        int l1 = __builtin_amdgcn_readlane((int)mylim, 16);
        int l2 = __builtin_amdgcn_readlane((int)mylim, 32);
        int l3 = __builtin_amdgcn_readlane((int)mylim, 48);
        int kmax = l0 > l1 ? l0 : l1; kmax = kmax > l2 ? kmax : l2; kmax = kmax > l3 ? kmax : l3;
        int kmin = l0 < l1 ? l0 : l1; kmin = kmin < l2 ? kmin : l2; kmin = kmin < l3 ? kmin : l3;

        int dwEnd = (kmax + 3) >> 2;
        int dwMin = kmin >> 2;
        int dwL   = dwEnd < SPLIT ? dwEnd : SPLIT;
        int dwLm  = dwMin < dwL ? dwMin : dwL;
        int dwGm  = dwMin < dwEnd ? dwMin : dwEnd;
        if (dwGm < SPLIT) dwGm = SPLIT;

        float4 e0, e1, e2, e3;                    // h(t+0..t+3) for quad q

        if (!__any((int)(cnt > (unsigned)sl))) {
            float h0 = bs.x, h1 = bs.y, h2 = bs.z, h3 = bs.w;
            for (int kd = 0;     kd < dwLm;  ++kd) B_LDS(kd, false);
            for (int kd = dwLm;  kd < dwL;   ++kd) B_LDS(kd, true);
            for (int kd = SPLIT; kd < dwGm;  ++kd) B_GLB(kd, false);
            for (int kd = dwGm;  kd < dwEnd; ++kd) B_GLB(kd, true);

            // exchange: every lane gets h(t+0..t+3) for its quad
            sEx[wave][lane] = make_float4(h0, h1, h2, h3);
            e0 = sEx[wave][q];
            e1 = sEx[wave][16 + q];
            e2 = sEx[wave][32 + q];
            e3 = sEx[wave][48 + q];
        } else {
            // ~never: some count exceeds slots -> recompute all 4 t's from x
#pragma unroll
            for (int tt = 0; tt < 4; ++tt) {
                const float* xr = x + ((size_t)(t + tt) * BB + ub) * NIN;
                float g0 = bs.x, g1 = bs.y, g2 = bs.z, g3 = bs.w;
                for (int w2 = 0; w2 < 4; ++w2) {
                    unsigned long long m = __ballot(xr[(w2 << 6) + lane] > 0.5f);
                    while (m) {
                        int i = (w2 << 6) + __builtin_ctzll(m);
                        m &= m - 1;
                        float4 v = sW4[i * 16 + q];
                        g0 += v.x; g1 += v.y; g2 += v.z; g3 += v.w;
                    }
                }
                if      (tt == 0) e0 = make_float4(g0, g1, g2, g3);
                else if (tt == 1) e1 = make_float4(g0, g1, g2, g3);
                else if (tt == 2) e2 = make_float4(g0, g1, g2, g3);
                else              e3 = make_float4(g0, g1, g2, g3);
            }
        }

        // 4 membrane steps (np fp32 semantics: mul, add separate), redundant
        // across all lanes so exec stays full.
#define MSTEP(hv, memv, spv) { float mm_ = 0.9f * (memv); mm_ = mm_ + (hv);     \
        spv = (mm_ - 1.0f > 0.0f) ? 1.0f : 0.0f; memv = mm_ - spv; }
        float sA0, sA1, sA2, sA3, sB0, sB1, sB2, sB3;
        float sC0, sC1, sC2, sC3, sD0, sD1, sD2, sD3;
        MSTEP(e0.x, mem0, sA0) MSTEP(e0.y, mem1, sA1) MSTEP(e0.z, mem2, sA2) MSTEP(e0.w, mem3, sA3)
        MSTEP(e1.x, mem0, sB0) MSTEP(e1.y, mem1, sB1) MSTEP(e1.z, mem2, sB2) MSTEP(e1.w, mem3, sB3)
        MSTEP(e2.x, mem0, sC0) MSTEP(e2.y, mem1, sC1) MSTEP(e2.z, mem2, sC2) MSTEP(e2.w, mem3, sC3)
        MSTEP(e3.x, mem0, sD0) MSTEP(e3.y, mem1, sD1) MSTEP(e3.z, mem2, sD2) MSTEP(e3.w, mem3, sD3)
#undef MSTEP

        // lane stores its own group's row (t+s)
        float4 sv;
        sv.x = sLo ? (sEven ? sA0 : sB0) : (sEven ? sC0 : sD0);
        sv.y = sLo ? (sEven ? sA1 : sB1) : (sEven ? sC1 : sD1);
        sv.z = sLo ? (sEven ? sA2 : sB2) : (sEven ? sC2 : sD2);
        sv.w = sLo ? (sEven ? sA3 : sB3) : (sEven ? sC3 : sD3);
        *reinterpret_cast<float4*>(outP) = sv;
        outP += outStep;
    }
#undef B_GLB
#undef B_LDS
#undef FETCH_D
#undef RL
}

// One wave per (t,b): bit-identical layer-2 tree to rounds 1-7:
// per chunk c (ascending 0..15): r = spk[c*64+lane]*W2[o][c*64+lane],
// xor-butterfly offs 32,16,8,4,2,1, accumulate; then + b2[o].
__global__ __launch_bounds__(256) void k_h2(const float* __restrict__ spk,
                                            const float* __restrict__ W2,
                                            const float* __restrict__ b2,
                                            float* __restrict__ h2) {
#pragma clang fp contract(off)
    const int lane = threadIdx.x & 63;
    const int wave = threadIdx.x >> 6;
    size_t tb = (size_t)blockIdx.x * 4 + wave;    // t*B + b
    const float* row = spk + tb * HID;
    float s0 = 0.0f, s1 = 0.0f;
#pragma unroll
    for (int c = 0; c < 16; ++c) {
        float v  = row[c * 64 + lane];
        float r0 = v * W2[c * 64 + lane];
        float r1 = v * W2[HID + c * 64 + lane];
#pragma unroll
        for (int off = 32; off > 0; off >>= 1) {
            r0 += __shfl_xor(r0, off, 64);
            r1 += __shfl_xor(r1, off, 64);
        }
        s0 += r0;
        s1 += r1;
    }
    s0 += b2[0];
    s1 += b2[1];
    if (lane == 0)
        *reinterpret_cast<float2*>(h2 + tb * 2) = make_float2(s0, s1);
}

__global__ __launch_bounds__(256) void k_scan(const float* __restrict__ h2,
                                              float* __restrict__ outSpk,
                                              float* __restrict__ outMem2) {
#pragma clang fp contract(off)
    const int tid = threadIdx.x;                  // b*2 + o
    float mem = 0.0f;
    float cur[8], nxt[8];
#pragma unroll
    for (int k = 0; k < 8; ++k) cur[k] = h2[k * 256 + tid];
    for (int t0 = 0; t0 < TT; t0 += 8) {
#pragma unroll
        for (int k = 0; k < 8; ++k) {
            int tn = t0 + 8 + k;
            nxt[k] = (tn < TT) ? h2[tn * 256 + tid] : 0.0f;
        }
#pragma unroll
        for (int k = 0; k < 8; ++k) {
            float mm = 0.9f * mem;
            mm = mm + cur[k];
            float spk = (mm - 1.0f > 0.0f) ? 1.0f : 0.0f;
            mm = mm - spk;
            mem = mm;
            outSpk[(t0 + k) * 256 + tid] = spk;
        }
#pragma unroll
        for (int k = 0; k < 8; ++k) cur[k] = nxt[k];
    }
    outMem2[tid] = mem;
}

extern "C" void kernel_launch(void* const* d_in, const int* in_sizes, int n_in,
                              void* d_out, int out_size, void* d_ws, size_t ws_size,
                              hipStream_t stream) {
    const float* x  = (const float*)d_in[0];
    const float* W1 = (const float*)d_in[1];
    const float* b1 = (const float*)d_in[2];
    const float* W2 = (const float*)d_in[3];
    const float* b2 = (const float*)d_in[4];
    float* out = (float*)d_out;

    char* ws = (char*)d_ws;
    float*         W1T = (float*)(ws);                                 // 257 rows ~1.03 MB
    unsigned int*  cnt = (unsigned int*)(ws + (2 << 20));              // 512 KB
    unsigned char* idx = (unsigned char*)(ws + (2 << 20) + (1 << 19)); // 131072*slots

    // size the index lists to the workspace (fallback path covers overflow)
    size_t fixedB = (size_t)(2 << 20) + (1 << 19) + (1 << 20);
    size_t avail  = ws_size > fixedB ? ws_size - fixedB : 0;
    long   s      = (long)((avail / 131072) & ~(size_t)7);
    int slots = (int)(s > 96 ? 96 : (s < 8 ? 8 : s));

    float* h2 = (float*)(ws + (2 << 20) + (1 << 19) + (size_t)131072 * (size_t)slots); // 1 MB

    k_transpose<<<1028, 256, 0, stream>>>(W1, W1T);
    k_pack<<<131072, 256, 0, stream>>>(x, cnt, idx, slots);
    k_snn<<<512, 256, 0, stream>>>(W1T, cnt, idx, x, b1, out + OFF_HID, slots);
    k_h2<<<32768, 256, 0, stream>>>(out + OFF_HID, W2, b2, h2);
    k_scan<<<1, 256, 0, stream>>>(h2, out, out + OFF_MEM2);
}

// Round 11
// 1224.203 us; speedup vs baseline: 1.0202x; 1.0202x over previous
//
#include <hip/hip_runtime.h>
#include <hip/hip_bf16.h>
#include <stdint.h>

// SNN forward (snntorch Leaky, subtract reset), T=1024 B=128 NIN=256 HID=1024.
// d_out: out_spikes [T,B,2] | hidden_spikes [T,B,HID] | mem2_f [B,2]
//
// Round-11 (= round-9 with the macro-pasting compile fix: window registers are
// letter-suffixed w0a..w3d because `0.x` lexes as one pp-number token).
// Round-7 skeleton + async hybrid fetch: index dwords 0..8 gathered from the
// 64KB LDS tile; dwords >=9 from L2-resident W1T via a 4-dword issue-ahead
// register window (16 global_load_dwordx4 in flight before the LDS phase,
// consume-and-reissue 4-wide; counted vmcnt, never drain-0). 32-bit voffsets
// (row<<8 float4 index). Reads reorder; ADDS stay strictly ascending-i ->
// bit-exact (absmax 0.0 across rounds 1-8). k_pack/k_h2/k_scan unchanged.

#define TT  1024
#define BB  128
#define NIN 256
#define HID 1024

#define OFF_HID  262144ULL
#define OFF_MEM2 134479872ULL

// W1T gets 257 rows: rows 0..255 = transpose, row 256 = zeros (predication pad)
__global__ __launch_bounds__(256) void k_transpose(const float* __restrict__ W1,
                                                   float* __restrict__ W1T) {
    int idx = blockIdx.x * 256 + threadIdx.x;     // 263168 = 257*1024 elements
    if (idx >= 257 * 1024) return;
    int j = idx & (HID - 1);
    int i = idx >> 10;
    W1T[(size_t)i * HID + j] = (i < NIN) ? W1[(size_t)j * NIN + i] : 0.0f;
}

__global__ __launch_bounds__(256) void k_pack(const float* __restrict__ x,
                                              unsigned int* __restrict__ cntArr,
                                              unsigned char* __restrict__ idxArr,
                                              int slots) {
    size_t tb = blockIdx.x;                       // T*B blocks, 256 threads = i
    int tid = threadIdx.x;
    int lane = tid & 63, w = tid >> 6;
    float v = x[tb * NIN + tid];
    bool act = v > 0.5f;
    unsigned long long m = __ballot(act);
    __shared__ unsigned int wc[4];
    __shared__ unsigned char sIdx[96];
    if (lane == 0) wc[w] = (unsigned int)__popcll(m);
    __syncthreads();
    unsigned int off = 0;
#pragma unroll
    for (int k = 0; k < 4; ++k) if (k < w) off += wc[k];
    unsigned int cnt = wc[0] + wc[1] + wc[2] + wc[3];
    unsigned int rank = off + (unsigned int)__popcll(m & ((1ull << lane) - 1));
    if (act && rank < (unsigned int)slots) sIdx[rank] = (unsigned char)tid;
    __syncthreads();
    if (tid * 4 < slots)
        ((unsigned int*)(idxArr + tb * (size_t)slots))[tid] = ((const unsigned int*)sIdx)[tid];
    if (tid == 0) cntArr[tb] = cnt;
}

// Workgroup = 4 waves = 4 b's sharing a 64-j chunk of W1T as [257 i][16 quads]
// float4 (64.3 KB LDS). lane = (s=lane>>4 t-subgroup, q=lane&15 quad).
// Grid = 32 bg x 16 jc = 512 wgs -> 2 wg/CU, 2 waves/SIMD.
__global__ __launch_bounds__(256, 2) void k_snn(const float* __restrict__ W1T,
                                                const unsigned int* __restrict__ cntArr,
                                                const unsigned char* __restrict__ idxArr,
                                                const float* __restrict__ x,
                                                const float* __restrict__ b1,
                                                float* __restrict__ outHid,
                                                int slots) {
#pragma clang fp contract(off)
    const int jc   = blockIdx.x & 15;
    const int bg   = blockIdx.x >> 4;
    const int tid  = threadIdx.x;
    const int lane = tid & 63;
    const int wave = tid >> 6;
    const int b    = (bg << 2) + wave;
    const int q    = lane & 15;                   // quad (4 j) within 64-j chunk
    const int s    = lane >> 4;                   // t-subgroup 0..3
    const int jq   = (jc << 6) + (q << 2);
    const int jq4  = jq >> 2;                     // float4 index of lane's quad

    __shared__ float4 sW4[257 * 16];              // 64.3 KB; row 256 = zeros
    __shared__ float4 sEx[4][64];                 // per-wave exchange scratch

    for (int p = tid; p < NIN * 16; p += 256) {
        int i = p >> 4, qq = p & 15;
        sW4[p] = *reinterpret_cast<const float4*>(W1T + (size_t)i * HID + (jc << 6) + (qq << 2));
    }
    if (tid < 16) sW4[256 * 16 + tid] = make_float4(0.f, 0.f, 0.f, 0.f);
    __syncthreads();

    float mem0 = 0.f, mem1 = 0.f, mem2 = 0.f, mem3 = 0.f;
    const float4 bs = *reinterpret_cast<const float4*>(b1 + jq);
    const int ub = __builtin_amdgcn_readfirstlane(b);
    const int sl = slots;
    const int dwTot = sl >> 2;
    int dwA = q;            if (dwA >= dwTot) dwA = dwTot - 1;
    int dwB = 16 + (q & 7); if (dwB >= dwTot) dwB = dwTot - 1;

    const bool sLo   = (s < 2);
    const bool sEven = ((s & 1) == 0);
    const float4* __restrict__ W1Tf4 = reinterpret_cast<const float4*>(W1T);

    // strength-reduced prefetch offsets (bytes), pointing at t = 0..3
    unsigned offCnt = (unsigned)((s * BB + ub) * 4);
    unsigned offA   = (unsigned)((s * BB + ub) * sl + dwA * 4);
    unsigned offB   = (unsigned)((s * BB + ub) * sl + dwB * 4);
    const unsigned stC = (unsigned)(4 * BB * 4);
    const unsigned stL = (unsigned)(4 * BB * sl);

    unsigned cnt_v = *(const unsigned*)((const char*)cntArr + offCnt);
    unsigned vA_v  = *(const unsigned*)(idxArr + offA);
    unsigned vB_v  = *(const unsigned*)(idxArr + offB);

    float* outP = outHid + ((size_t)s * BB + b) * HID + jq;
    const size_t outStep = (size_t)4 * BB * HID;

#define RL(v, l) ((unsigned)__builtin_amdgcn_readlane((int)(v), (l)))
#define FETCH_D(kd, dOut) do {                                                  \
        unsigned _d0, _d1, _d2, _d3;                                            \
        if ((kd) < 16) {                                                        \
            _d0 = RL(vA, (kd));      _d1 = RL(vA, 16 + (kd));                   \
            _d2 = RL(vA, 32 + (kd)); _d3 = RL(vA, 48 + (kd));                   \
        } else { int _m = (kd) - 16;                                            \
            _d0 = RL(vB, _m);        _d1 = RL(vB, 16 + _m);                     \
            _d2 = RL(vB, 32 + _m);   _d3 = RL(vB, 48 + _m); }                   \
        unsigned _dl = sEven ? _d0 : _d1;                                       \
        unsigned _dh = sEven ? _d2 : _d3;                                       \
        dOut = sLo ? _dl : _dh;                                                 \
    } while (0)

#define B_LDS(kd, PRED) do {                                                    \
        unsigned d_; FETCH_D(kd, d_);                                           \
        int kb_ = (kd) << 2;                                                    \
        _Pragma("unroll")                                                       \
        for (int i2 = 0; i2 < 4; ++i2) {                                        \
            unsigned row_ = (d_ >> (8 * i2)) & 255u;                            \
            if (PRED) row_ = ((unsigned)(kb_ + i2) < mylim) ? row_ : 256u;      \
            float4 v_ = sW4[row_ * 16 + q];                                     \
            h0 += v_.x; h1 += v_.y; h2 += v_.z; h3 += v_.w;                     \
        }                                                                       \
    } while (0)

    // issue one dword's 4 global float4 loads into window slot n (predicated
    // to zero-row 256; 32-bit voffset row<<8 + jq4 -> single lshl_add + load)
#define WISS(n) do {                                                            \
        if (isu < dwEnd) {                                                      \
            unsigned d_; FETCH_D(isu, d_);                                      \
            int kb_ = isu << 2;                                                 \
            unsigned r0_ = d_ & 255u, r1_ = (d_ >> 8) & 255u;                   \
            unsigned r2_ = (d_ >> 16) & 255u, r3_ = d_ >> 24;                   \
            r0_ = ((unsigned)(kb_    ) < mylim) ? r0_ : 256u;                   \
            r1_ = ((unsigned)(kb_ + 1) < mylim) ? r1_ : 256u;                   \
            r2_ = ((unsigned)(kb_ + 2) < mylim) ? r2_ : 256u;                   \
            r3_ = ((unsigned)(kb_ + 3) < mylim) ? r3_ : 256u;                   \
            w##n##a = W1Tf4[(r0_ << 8) + jq4];                                  \
            w##n##b = W1Tf4[(r1_ << 8) + jq4];                                  \
            w##n##c = W1Tf4[(r2_ << 8) + jq4];                                  \
            w##n##d = W1Tf4[(r3_ << 8) + jq4];                                  \
            ++isu;                                                              \
        }                                                                       \
    } while (0)

#define WCON(n) do {                                                            \
        h0 += w##n##a.x; h1 += w##n##a.y; h2 += w##n##a.z; h3 += w##n##a.w;     \
        h0 += w##n##b.x; h1 += w##n##b.y; h2 += w##n##b.z; h3 += w##n##b.w;     \
        h0 += w##n##c.x; h1 += w##n##c.y; h2 += w##n##c.z; h3 += w##n##c.w;     \
        h0 += w##n##d.x; h1 += w##n##d.y; h2 += w##n##d.z; h3 += w##n##d.w;     \
    } while (0)

    const int SPLIT = 9;                          // dwords via LDS (k < 36)

    for (int t = 0; t < TT; t += 4) {
        unsigned cnt = cnt_v, vA = vA_v, vB = vB_v;

        // prefetch t+4 (clamped via zero stride on last iter)
        unsigned st = (t + 4 < TT) ? 1u : 0u;
        offCnt += st * stC; offA += st * stL; offB += st * stL;
        cnt_v = *(const unsigned*)((const char*)cntArr + offCnt);
        vA_v  = *(const unsigned*)(idxArr + offA);
        vB_v  = *(const unsigned*)(idxArr + offB);

        unsigned mylim = cnt < (unsigned)sl ? cnt : (unsigned)sl;
        int l0 = __builtin_amdgcn_readlane((int)mylim, 0);
        int l1 = __builtin_amdgcn_readlane((int)mylim, 16);
        int l2 = __builtin_amdgcn_readlane((int)mylim, 32);
        int l3 = __builtin_amdgcn_readlane((int)mylim, 48);
        int kmax = l0 > l1 ? l0 : l1; kmax = kmax > l2 ? kmax : l2; kmax = kmax > l3 ? kmax : l3;
        int kmin = l0 < l1 ? l0 : l1; kmin = kmin < l2 ? kmin : l2; kmin = kmin < l3 ? kmin : l3;

        int dwEnd = (kmax + 3) >> 2;
        int dwL   = dwEnd < SPLIT ? dwEnd : SPLIT;
        int dwLm  = (kmin >> 2) < dwL ? (kmin >> 2) : dwL;

        float4 e0, e1, e2, e3;                    // h(t+0..t+3) for quad q

        if (!__any((int)(cnt > (unsigned)sl))) {
            float h0 = bs.x, h1 = bs.y, h2 = bs.z, h3 = bs.w;

            // ---- issue-ahead window: 4 dwords of global loads in flight ----
            float4 w0a, w0b, w0c, w0d;
            float4 w1a, w1b, w1c, w1d;
            float4 w2a, w2b, w2c, w2d;
            float4 w3a, w3b, w3c, w3d;
            int isu = SPLIT;
            WISS(0); WISS(1); WISS(2); WISS(3);

            // ---- LDS phase: dwords 0..dwL (ascending-i adds) ----
            int kd = 0;
            for (; kd < dwLm; ++kd) B_LDS(kd, false);
            for (; kd < dwL;  ++kd) B_LDS(kd, true);

            // ---- consume window 4-wide, reissue as we go ----
            int kc = SPLIT;
            for (; kc + 4 <= dwEnd; kc += 4) {
                WCON(0); WISS(0);
                WCON(1); WISS(1);
                WCON(2); WISS(2);
                WCON(3); WISS(3);
            }
            int rem = dwEnd - kc;
            if (rem > 0) WCON(0);
            if (rem > 1) WCON(1);
            if (rem > 2) WCON(2);

            // exchange: every lane gets h(t+0..t+3) for its quad
            sEx[wave][lane] = make_float4(h0, h1, h2, h3);
            e0 = sEx[wave][q];
            e1 = sEx[wave][16 + q];
            e2 = sEx[wave][32 + q];
            e3 = sEx[wave][48 + q];
        } else {
            // ~never: some count exceeds slots -> recompute all 4 t's from x
#pragma unroll
            for (int tt = 0; tt < 4; ++tt) {
                const float* xr = x + ((size_t)(t + tt) * BB + ub) * NIN;
                float g0 = bs.x, g1 = bs.y, g2 = bs.z, g3 = bs.w;
                for (int w2 = 0; w2 < 4; ++w2) {
                    unsigned long long m = __ballot(xr[(w2 << 6) + lane] > 0.5f);
                    while (m) {
                        int i = (w2 << 6) + __builtin_ctzll(m);
                        m &= m - 1;
                        float4 v = sW4[i * 16 + q];
                        g0 += v.x; g1 += v.y; g2 += v.z; g3 += v.w;
                    }
                }
                if      (tt == 0) e0 = make_float4(g0, g1, g2, g3);
                else if (tt == 1) e1 = make_float4(g0, g1, g2, g3);
                else if (tt == 2) e2 = make_float4(g0, g1, g2, g3);
                else              e3 = make_float4(g0, g1, g2, g3);
            }
        }

        // 4 membrane steps (np fp32 semantics: mul, add separate), redundant
        // across all lanes so exec stays full.
#define MSTEP(hv, memv, spv) { float mm_ = 0.9f * (memv); mm_ = mm_ + (hv);     \
        spv = (mm_ - 1.0f > 0.0f) ? 1.0f : 0.0f; memv = mm_ - spv; }
        float sA0, sA1, sA2, sA3, sB0, sB1, sB2, sB3;
        float sC0, sC1, sC2, sC3, sD0, sD1, sD2, sD3;
        MSTEP(e0.x, mem0, sA0) MSTEP(e0.y, mem1, sA1) MSTEP(e0.z, mem2, sA2) MSTEP(e0.w, mem3, sA3)
        MSTEP(e1.x, mem0, sB0) MSTEP(e1.y, mem1, sB1) MSTEP(e1.z, mem2, sB2) MSTEP(e1.w, mem3, sB3)
        MSTEP(e2.x, mem0, sC0) MSTEP(e2.y, mem1, sC1) MSTEP(e2.z, mem2, sC2) MSTEP(e2.w, mem3, sC3)
        MSTEP(e3.x, mem0, sD0) MSTEP(e3.y, mem1, sD1) MSTEP(e3.z, mem2, sD2) MSTEP(e3.w, mem3, sD3)
#undef MSTEP

        // lane stores its own group's row (t+s)
        float4 sv;
        sv.x = sLo ? (sEven ? sA0 : sB0) : (sEven ? sC0 : sD0);
        sv.y = sLo ? (sEven ? sA1 : sB1) : (sEven ? sC1 : sD1);
        sv.z = sLo ? (sEven ? sA2 : sB2) : (sEven ? sC2 : sD2);
        sv.w = sLo ? (sEven ? sA3 : sB3) : (sEven ? sC3 : sD3);
        *reinterpret_cast<float4*>(outP) = sv;
        outP += outStep;
    }
#undef WCON
#undef WISS
#undef B_LDS
#undef FETCH_D
#undef RL
}

// One wave per (t,b): bit-identical layer-2 tree to rounds 1-8:
// per chunk c (ascending 0..15): r = spk[c*64+lane]*W2[o][c*64+lane],
// xor-butterfly offs 32,16,8,4,2,1, accumulate; then + b2[o].
__global__ __launch_bounds__(256) void k_h2(const float* __restrict__ spk,
                                            const float* __restrict__ W2,
                                            const float* __restrict__ b2,
                                            float* __restrict__ h2) {
#pragma clang fp contract(off)
    const int lane = threadIdx.x & 63;
    const int wave = threadIdx.x >> 6;
    size_t tb = (size_t)blockIdx.x * 4 + wave;    // t*B + b
    const float* row = spk + tb * HID;
    float s0 = 0.0f, s1 = 0.0f;
#pragma unroll
    for (int c = 0; c < 16; ++c) {
        float v  = row[c * 64 + lane];
        float r0 = v * W2[c * 64 + lane];
        float r1 = v * W2[HID + c * 64 + lane];
#pragma unroll
        for (int off = 32; off > 0; off >>= 1) {
            r0 += __shfl_xor(r0, off, 64);
            r1 += __shfl_xor(r1, off, 64);
        }
        s0 += r0;
        s1 += r1;
    }
    s0 += b2[0];
    s1 += b2[1];
    if (lane == 0)
        *reinterpret_cast<float2*>(h2 + tb * 2) = make_float2(s0, s1);
}

__global__ __launch_bounds__(256) void k_scan(const float* __restrict__ h2,
                                              float* __restrict__ outSpk,
                                              float* __restrict__ outMem2) {
#pragma clang fp contract(off)
    const int tid = threadIdx.x;                  // b*2 + o
    float mem = 0.0f;
    float cur[8], nxt[8];
#pragma unroll
    for (int k = 0; k < 8; ++k) cur[k] = h2[k * 256 + tid];
    for (int t0 = 0; t0 < TT; t0 += 8) {
#pragma unroll
        for (int k = 0; k < 8; ++k) {
            int tn = t0 + 8 + k;
            nxt[k] = (tn < TT) ? h2[tn * 256 + tid] : 0.0f;
        }
#pragma unroll
        for (int k = 0; k < 8; ++k) {
            float mm = 0.9f * mem;
            mm = mm + cur[k];
            float spk = (mm - 1.0f > 0.0f) ? 1.0f : 0.0f;
            mm = mm - spk;
            mem = mm;
            outSpk[(t0 + k) * 256 + tid] = spk;
        }
#pragma unroll
        for (int k = 0; k < 8; ++k) cur[k] = nxt[k];
    }
    outMem2[tid] = mem;
}

extern "C" void kernel_launch(void* const* d_in, const int* in_sizes, int n_in,
                              void* d_out, int out_size, void* d_ws, size_t ws_size,
                              hipStream_t stream) {
    const float* x  = (const float*)d_in[0];
    const float* W1 = (const float*)d_in[1];
    const float* b1 = (const float*)d_in[2];
    const float* W2 = (const float*)d_in[3];
    const float* b2 = (const float*)d_in[4];
    float* out = (float*)d_out;

    char* ws = (char*)d_ws;
    float*         W1T = (float*)(ws);                                 // 257 rows ~1.03 MB
    unsigned int*  cnt = (unsigned int*)(ws + (2 << 20));              // 512 KB
    unsigned char* idx = (unsigned char*)(ws + (2 << 20) + (1 << 19)); // 131072*slots

    // size the index lists to the workspace (fallback path covers overflow)
    size_t fixedB = (size_t)(2 << 20) + (1 << 19) + (1 << 20);
    size_t avail  = ws_size > fixedB ? ws_size - fixedB : 0;
    long   s      = (long)((avail / 131072) & ~(size_t)7);
    int slots = (int)(s > 96 ? 96 : (s < 8 ? 8 : s));

    float* h2 = (float*)(ws + (2 << 20) + (1 << 19) + (size_t)131072 * (size_t)slots); // 1 MB

    k_transpose<<<1028, 256, 0, stream>>>(W1, W1T);
    k_pack<<<131072, 256, 0, stream>>>(x, cnt, idx, slots);
    k_snn<<<512, 256, 0, stream>>>(W1T, cnt, idx, x, b1, out + OFF_HID, slots);
    k_h2<<<32768, 256, 0, stream>>>(out + OFF_HID, W2, b2, h2);
    k_scan<<<1, 256, 0, stream>>>(h2, out, out + OFF_MEM2);
}

// Round 12
// 1199.693 us; speedup vs baseline: 1.0410x; 1.0204x over previous
//
#include <hip/hip_runtime.h>
#include <hip/hip_bf16.h>
#include <stdint.h>

// SNN forward (snntorch Leaky, subtract reset), T=1024 B=128 NIN=256 HID=1024.
// d_out: out_spikes [T,B,2] | hidden_spikes [T,B,HID] | mem2_f [B,2]
//
// Round-12: R11 is VALU-issue bound (66% busy, DS/VMEM under). Changes:
//  - float2 (ext_vector) accumulators h01/h23 -> v_pk_add_f32 halves the
//    useful-add instruction count. Per-slot IEEE fp32, per-j chains unchanged
//    (bias -> strictly ascending active i) -> bit-exact.
//  - membrane steps in pk form (mul/add/sub packed, cmp scalar) - same bits.
//  - WISS predication behind a wave-uniform branch (isu >= kmin/4 only).
//  - B_LDS fetch uses vA directly (SPLIT=9 < 16, no runtime 16-branch).
// k_pack/k_h2/k_scan/k_transpose unchanged (absmax 0.0 rounds 1-11).

#define TT  1024
#define BB  128
#define NIN 256
#define HID 1024

#define OFF_HID  262144ULL
#define OFF_MEM2 134479872ULL

typedef float f2 __attribute__((ext_vector_type(2)));

// W1T gets 257 rows: rows 0..255 = transpose, row 256 = zeros (predication pad)
__global__ __launch_bounds__(256) void k_transpose(const float* __restrict__ W1,
                                                   float* __restrict__ W1T) {
    int idx = blockIdx.x * 256 + threadIdx.x;     // 263168 = 257*1024 elements
    if (idx >= 257 * 1024) return;
    int j = idx & (HID - 1);
    int i = idx >> 10;
    W1T[(size_t)i * HID + j] = (i < NIN) ? W1[(size_t)j * NIN + i] : 0.0f;
}

__global__ __launch_bounds__(256) void k_pack(const float* __restrict__ x,
                                              unsigned int* __restrict__ cntArr,
                                              unsigned char* __restrict__ idxArr,
                                              int slots) {
    size_t tb = blockIdx.x;                       // T*B blocks, 256 threads = i
    int tid = threadIdx.x;
    int lane = tid & 63, w = tid >> 6;
    float v = x[tb * NIN + tid];
    bool act = v > 0.5f;
    unsigned long long m = __ballot(act);
    __shared__ unsigned int wc[4];
    __shared__ unsigned char sIdx[96];
    if (lane == 0) wc[w] = (unsigned int)__popcll(m);
    __syncthreads();
    unsigned int off = 0;
#pragma unroll
    for (int k = 0; k < 4; ++k) if (k < w) off += wc[k];
    unsigned int cnt = wc[0] + wc[1] + wc[2] + wc[3];
    unsigned int rank = off + (unsigned int)__popcll(m & ((1ull << lane) - 1));
    if (act && rank < (unsigned int)slots) sIdx[rank] = (unsigned char)tid;
    __syncthreads();
    if (tid * 4 < slots)
        ((unsigned int*)(idxArr + tb * (size_t)slots))[tid] = ((const unsigned int*)sIdx)[tid];
    if (tid == 0) cntArr[tb] = cnt;
}

// Workgroup = 4 waves = 4 b's sharing a 64-j chunk of W1T as [257 i][16 quads]
// float4 (64.3 KB LDS). lane = (s=lane>>4 t-subgroup, q=lane&15 quad).
// Grid = 32 bg x 16 jc = 512 wgs -> 2 wg/CU, 2 waves/SIMD.
__global__ __launch_bounds__(256, 2) void k_snn(const float* __restrict__ W1T,
                                                const unsigned int* __restrict__ cntArr,
                                                const unsigned char* __restrict__ idxArr,
                                                const float* __restrict__ x,
                                                const float* __restrict__ b1,
                                                float* __restrict__ outHid,
                                                int slots) {
#pragma clang fp contract(off)
    const int jc   = blockIdx.x & 15;
    const int bg   = blockIdx.x >> 4;
    const int tid  = threadIdx.x;
    const int lane = tid & 63;
    const int wave = tid >> 6;
    const int b    = (bg << 2) + wave;
    const int q    = lane & 15;                   // quad (4 j) within 64-j chunk
    const int s    = lane >> 4;                   // t-subgroup 0..3
    const int jq   = (jc << 6) + (q << 2);
    const int jq4  = jq >> 2;                     // float4 index of lane's quad

    __shared__ float4 sW4[257 * 16];              // 64.3 KB; row 256 = zeros
    __shared__ float4 sEx[4][64];                 // per-wave exchange scratch

    for (int p = tid; p < NIN * 16; p += 256) {
        int i = p >> 4, qq = p & 15;
        sW4[p] = *reinterpret_cast<const float4*>(W1T + (size_t)i * HID + (jc << 6) + (qq << 2));
    }
    if (tid < 16) sW4[256 * 16 + tid] = make_float4(0.f, 0.f, 0.f, 0.f);
    __syncthreads();

    f2 mem01, mem23;
    mem01.x = 0.f; mem01.y = 0.f; mem23.x = 0.f; mem23.y = 0.f;
    const float4 bs = *reinterpret_cast<const float4*>(b1 + jq);
    const int ub = __builtin_amdgcn_readfirstlane(b);
    const int sl = slots;
    const int dwTot = sl >> 2;
    int dwA = q;            if (dwA >= dwTot) dwA = dwTot - 1;
    int dwB = 16 + (q & 7); if (dwB >= dwTot) dwB = dwTot - 1;

    const bool sLo   = (s < 2);
    const bool sEven = ((s & 1) == 0);
    const float4* __restrict__ W1Tf4 = reinterpret_cast<const float4*>(W1T);

    // strength-reduced prefetch offsets (bytes), pointing at t = 0..3
    unsigned offCnt = (unsigned)((s * BB + ub) * 4);
    unsigned offA   = (unsigned)((s * BB + ub) * sl + dwA * 4);
    unsigned offB   = (unsigned)((s * BB + ub) * sl + dwB * 4);
    const unsigned stC = (unsigned)(4 * BB * 4);
    const unsigned stL = (unsigned)(4 * BB * sl);

    unsigned cnt_v = *(const unsigned*)((const char*)cntArr + offCnt);
    unsigned vA_v  = *(const unsigned*)(idxArr + offA);
    unsigned vB_v  = *(const unsigned*)(idxArr + offB);

    float* outP = outHid + ((size_t)s * BB + b) * HID + jq;
    const size_t outStep = (size_t)4 * BB * HID;

#define RL(v, l) ((unsigned)__builtin_amdgcn_readlane((int)(v), (l)))
    // full fetch (kd may be >=16): used by WISS
#define FETCH_D(kd, dOut) do {                                                  \
        unsigned _d0, _d1, _d2, _d3;                                            \
        if ((kd) < 16) {                                                        \
            _d0 = RL(vA, (kd));      _d1 = RL(vA, 16 + (kd));                   \
            _d2 = RL(vA, 32 + (kd)); _d3 = RL(vA, 48 + (kd));                   \
        } else { int _m = (kd) - 16;                                            \
            _d0 = RL(vB, _m);        _d1 = RL(vB, 16 + _m);                     \
            _d2 = RL(vB, 32 + _m);   _d3 = RL(vB, 48 + _m); }                   \
        unsigned _dl = sEven ? _d0 : _d1;                                       \
        unsigned _dh = sEven ? _d2 : _d3;                                       \
        dOut = sLo ? _dl : _dh;                                                 \
    } while (0)

    // LDS-phase fetch: kd < SPLIT(9) <= 15 always -> vA only, no 16-branch
#define FETCH_A(kd, dOut) do {                                                  \
        unsigned _d0 = RL(vA, (kd));      unsigned _d1 = RL(vA, 16 + (kd));     \
        unsigned _d2 = RL(vA, 32 + (kd)); unsigned _d3 = RL(vA, 48 + (kd));     \
        unsigned _dl = sEven ? _d0 : _d1;                                       \
        unsigned _dh = sEven ? _d2 : _d3;                                       \
        dOut = sLo ? _dl : _dh;                                                 \
    } while (0)

#define B_LDS(kd, PRED) do {                                                    \
        unsigned d_; FETCH_A(kd, d_);                                           \
        int kb_ = (kd) << 2;                                                    \
        _Pragma("unroll")                                                       \
        for (int i2 = 0; i2 < 4; ++i2) {                                        \
            unsigned row_ = (d_ >> (8 * i2)) & 255u;                            \
            if (PRED) row_ = ((unsigned)(kb_ + i2) < mylim) ? row_ : 256u;      \
            float4 v_ = sW4[row_ * 16 + q];                                     \
            f2 ta_; ta_.x = v_.x; ta_.y = v_.y;                                 \
            f2 tb_; tb_.x = v_.z; tb_.y = v_.w;                                 \
            h01 += ta_;  h23 += tb_;               /* v_pk_add_f32, ascending-i */ \
        }                                                                       \
    } while (0)

    // issue one dword's 4 global float4 loads into window slot n; predication
    // only past kmin (wave-uniform branch)
#define WISS(n) do {                                                            \
        if (isu < dwEnd) {                                                      \
            unsigned d_; FETCH_D(isu, d_);                                      \
            unsigned r0_ = d_ & 255u, r1_ = (d_ >> 8) & 255u;                   \
            unsigned r2_ = (d_ >> 16) & 255u, r3_ = d_ >> 24;                   \
            if (isu >= predFrom) {                                              \
                int kb_ = isu << 2;                                             \
                r0_ = ((unsigned)(kb_    ) < mylim) ? r0_ : 256u;               \
                r1_ = ((unsigned)(kb_ + 1) < mylim) ? r1_ : 256u;               \
                r2_ = ((unsigned)(kb_ + 2) < mylim) ? r2_ : 256u;               \
                r3_ = ((unsigned)(kb_ + 3) < mylim) ? r3_ : 256u;               \
            }                                                                   \
            w##n##a = W1Tf4[(r0_ << 8) + jq4];                                  \
            w##n##b = W1Tf4[(r1_ << 8) + jq4];                                  \
            w##n##c = W1Tf4[(r2_ << 8) + jq4];                                  \
            w##n##d = W1Tf4[(r3_ << 8) + jq4];                                  \
            ++isu;                                                              \
        }                                                                       \
    } while (0)

#define PKADD(vv) do {                                                          \
        f2 ta_; ta_.x = vv.x; ta_.y = vv.y;                                     \
        f2 tb_; tb_.x = vv.z; tb_.y = vv.w;                                     \
        h01 += ta_;  h23 += tb_;                                                \
    } while (0)

#define WCON(n) do { PKADD(w##n##a); PKADD(w##n##b); PKADD(w##n##c); PKADD(w##n##d); } while (0)

    const int SPLIT = 9;                          // dwords via LDS (k < 36)

    for (int t = 0; t < TT; t += 4) {
        unsigned cnt = cnt_v, vA = vA_v, vB = vB_v;

        // prefetch t+4 (clamped via zero stride on last iter)
        unsigned st = (t + 4 < TT) ? 1u : 0u;
        offCnt += st * stC; offA += st * stL; offB += st * stL;
        cnt_v = *(const unsigned*)((const char*)cntArr + offCnt);
        vA_v  = *(const unsigned*)(idxArr + offA);
        vB_v  = *(const unsigned*)(idxArr + offB);

        unsigned mylim = cnt < (unsigned)sl ? cnt : (unsigned)sl;
        int l0 = __builtin_amdgcn_readlane((int)mylim, 0);
        int l1 = __builtin_amdgcn_readlane((int)mylim, 16);
        int l2 = __builtin_amdgcn_readlane((int)mylim, 32);
        int l3 = __builtin_amdgcn_readlane((int)mylim, 48);
        int kmax = l0 > l1 ? l0 : l1; kmax = kmax > l2 ? kmax : l2; kmax = kmax > l3 ? kmax : l3;
        int kmin = l0 < l1 ? l0 : l1; kmin = kmin < l2 ? kmin : l2; kmin = kmin < l3 ? kmin : l3;

        int dwEnd = (kmax + 3) >> 2;
        int dwL   = dwEnd < SPLIT ? dwEnd : SPLIT;
        int dwLm  = (kmin >> 2) < dwL ? (kmin >> 2) : dwL;
        int predFrom = kmin >> 2;

        float4 e0, e1, e2, e3;                    // h(t+0..t+3) for quad q

        if (!__any((int)(cnt > (unsigned)sl))) {
            f2 h01, h23;
            h01.x = bs.x; h01.y = bs.y; h23.x = bs.z; h23.y = bs.w;

            // ---- issue-ahead window: 4 dwords of global loads in flight ----
            float4 w0a, w0b, w0c, w0d;
            float4 w1a, w1b, w1c, w1d;
            float4 w2a, w2b, w2c, w2d;
            float4 w3a, w3b, w3c, w3d;
            int isu = SPLIT;
            WISS(0); WISS(1); WISS(2); WISS(3);

            // ---- LDS phase: dwords 0..dwL (ascending-i adds) ----
            int kd = 0;
            for (; kd < dwLm; ++kd) B_LDS(kd, false);
            for (; kd < dwL;  ++kd) B_LDS(kd, true);

            // ---- consume window 4-wide, reissue as we go ----
            int kc = SPLIT;
            for (; kc + 4 <= dwEnd; kc += 4) {
                WCON(0); WISS(0);
                WCON(1); WISS(1);
                WCON(2); WISS(2);
                WCON(3); WISS(3);
            }
            int rem = dwEnd - kc;
            if (rem > 0) WCON(0);
            if (rem > 1) WCON(1);
            if (rem > 2) WCON(2);

            // exchange: every lane gets h(t+0..t+3) for its quad
            sEx[wave][lane] = make_float4(h01.x, h01.y, h23.x, h23.y);
            e0 = sEx[wave][q];
            e1 = sEx[wave][16 + q];
            e2 = sEx[wave][32 + q];
            e3 = sEx[wave][48 + q];
        } else {
            // ~never: some count exceeds slots -> recompute all 4 t's from x
#pragma unroll
            for (int tt = 0; tt < 4; ++tt) {
                const float* xr = x + ((size_t)(t + tt) * BB + ub) * NIN;
                float g0 = bs.x, g1 = bs.y, g2 = bs.z, g3 = bs.w;
                for (int w2 = 0; w2 < 4; ++w2) {
                    unsigned long long m = __ballot(xr[(w2 << 6) + lane] > 0.5f);
                    while (m) {
                        int i = (w2 << 6) + __builtin_ctzll(m);
                        m &= m - 1;
                        float4 v = sW4[i * 16 + q];
                        g0 += v.x; g1 += v.y; g2 += v.z; g3 += v.w;
                    }
                }
                if      (tt == 0) e0 = make_float4(g0, g1, g2, g3);
                else if (tt == 1) e1 = make_float4(g0, g1, g2, g3);
                else if (tt == 2) e2 = make_float4(g0, g1, g2, g3);
                else              e3 = make_float4(g0, g1, g2, g3);
            }
        }

        // 4 membrane steps (np fp32 semantics: mul, add separate; packed ops
        // are per-slot IEEE fp32 -> bit-identical), redundant across lanes.
#define MSTEP4(ev, so0, so1, so2, so3) {                                        \
        f2 ha_, hb_, mmA_, mmB_, sp_;                                           \
        ha_.x = ev.x; ha_.y = ev.y; hb_.x = ev.z; hb_.y = ev.w;                 \
        mmA_ = 0.9f * mem01; mmA_ = mmA_ + ha_;                                 \
        so0 = (mmA_.x - 1.0f > 0.0f) ? 1.0f : 0.0f;                             \
        so1 = (mmA_.y - 1.0f > 0.0f) ? 1.0f : 0.0f;                             \
        sp_.x = so0; sp_.y = so1; mem01 = mmA_ - sp_;                           \
        mmB_ = 0.9f * mem23; mmB_ = mmB_ + hb_;                                 \
        so2 = (mmB_.x - 1.0f > 0.0f) ? 1.0f : 0.0f;                             \
        so3 = (mmB_.y - 1.0f > 0.0f) ? 1.0f : 0.0f;                             \
        sp_.x = so2; sp_.y = so3; mem23 = mmB_ - sp_;                           \
    }
        float sA0, sA1, sA2, sA3, sB0, sB1, sB2, sB3;
        float sC0, sC1, sC2, sC3, sD0, sD1, sD2, sD3;
        MSTEP4(e0, sA0, sA1, sA2, sA3)
        MSTEP4(e1, sB0, sB1, sB2, sB3)
        MSTEP4(e2, sC0, sC1, sC2, sC3)
        MSTEP4(e3, sD0, sD1, sD2, sD3)
#undef MSTEP4

        // lane stores its own group's row (t+s)
        float4 sv;
        sv.x = sLo ? (sEven ? sA0 : sB0) : (sEven ? sC0 : sD0);
        sv.y = sLo ? (sEven ? sA1 : sB1) : (sEven ? sC1 : sD1);
        sv.z = sLo ? (sEven ? sA2 : sB2) : (sEven ? sC2 : sD2);
        sv.w = sLo ? (sEven ? sA3 : sB3) : (sEven ? sC3 : sD3);
        *reinterpret_cast<float4*>(outP) = sv;
        outP += outStep;
    }
#undef WCON
#undef PKADD
#undef WISS
#undef B_LDS
#undef FETCH_A
#undef FETCH_D
#undef RL
}

// One wave per (t,b): bit-identical layer-2 tree to rounds 1-11:
// per chunk c (ascending 0..15): r = spk[c*64+lane]*W2[o][c*64+lane],
// xor-butterfly offs 32,16,8,4,2,1, accumulate; then + b2[o].
__global__ __launch_bounds__(256) void k_h2(const float* __restrict__ spk,
                                            const float* __restrict__ W2,
                                            const float* __restrict__ b2,
                                            float* __restrict__ h2) {
#pragma clang fp contract(off)
    const int lane = threadIdx.x & 63;
    const int wave = threadIdx.x >> 6;
    size_t tb = (size_t)blockIdx.x * 4 + wave;    // t*B + b
    const float* row = spk + tb * HID;
    float s0 = 0.0f, s1 = 0.0f;
#pragma unroll
    for (int c = 0; c < 16; ++c) {
        float v  = row[c * 64 + lane];
        float r0 = v * W2[c * 64 + lane];
        float r1 = v * W2[HID + c * 64 + lane];
#pragma unroll
        for (int off = 32; off > 0; off >>= 1) {
            r0 += __shfl_xor(r0, off, 64);
            r1 += __shfl_xor(r1, off, 64);
        }
        s0 += r0;
        s1 += r1;
    }
    s0 += b2[0];
    s1 += b2[1];
    if (lane == 0)
        *reinterpret_cast<float2*>(h2 + tb * 2) = make_float2(s0, s1);
}

__global__ __launch_bounds__(256) void k_scan(const float* __restrict__ h2,
                                              float* __restrict__ outSpk,
                                              float* __restrict__ outMem2) {
#pragma clang fp contract(off)
    const int tid = threadIdx.x;                  // b*2 + o
    float mem = 0.0f;
    float cur[8], nxt[8];
#pragma unroll
    for (int k = 0; k < 8; ++k) cur[k] = h2[k * 256 + tid];
    for (int t0 = 0; t0 < TT; t0 += 8) {
#pragma unroll
        for (int k = 0; k < 8; ++k) {
            int tn = t0 + 8 + k;
            nxt[k] = (tn < TT) ? h2[tn * 256 + tid] : 0.0f;
        }
#pragma unroll
        for (int k = 0; k < 8; ++k) {
            float mm = 0.9f * mem;
            mm = mm + cur[k];
            float spk = (mm - 1.0f > 0.0f) ? 1.0f : 0.0f;
            mm = mm - spk;
            mem = mm;
            outSpk[(t0 + k) * 256 + tid] = spk;
        }
#pragma unroll
        for (int k = 0; k < 8; ++k) cur[k] = nxt[k];
    }
    outMem2[tid] = mem;
}

extern "C" void kernel_launch(void* const* d_in, const int* in_sizes, int n_in,
                              void* d_out, int out_size, void* d_ws, size_t ws_size,
                              hipStream_t stream) {
    const float* x  = (const float*)d_in[0];
    const float* W1 = (const float*)d_in[1];
    const float* b1 = (const float*)d_in[2];
    const float* W2 = (const float*)d_in[3];
    const float* b2 = (const float*)d_in[4];
    float* out = (float*)d_out;

    char* ws = (char*)d_ws;
    float*         W1T = (float*)(ws);                                 // 257 rows ~1.03 MB
    unsigned int*  cnt = (unsigned int*)(ws + (2 << 20));              // 512 KB
    unsigned char* idx = (unsigned char*)(ws + (2 << 20) + (1 << 19)); // 131072*slots

    // size the index lists to the workspace (fallback path covers overflow)
    size_t fixedB = (size_t)(2 << 20) + (1 << 19) + (1 << 20);
    size_t avail  = ws_size > fixedB ? ws_size - fixedB : 0;
    long   s      = (long)((avail / 131072) & ~(size_t)7);
    int slots = (int)(s > 96 ? 96 : (s < 8 ? 8 : s));

    float* h2 = (float*)(ws + (2 << 20) + (1 << 19) + (size_t)131072 * (size_t)slots); // 1 MB

    k_transpose<<<1028, 256, 0, stream>>>(W1, W1T);
    k_pack<<<131072, 256, 0, stream>>>(x, cnt, idx, slots);
    k_snn<<<512, 256, 0, stream>>>(W1T, cnt, idx, x, b1, out + OFF_HID, slots);
    k_h2<<<32768, 256, 0, stream>>>(out + OFF_HID, W2, b2, h2);
    k_scan<<<1, 256, 0, stream>>>(h2, out, out + OFF_MEM2);
}